// Round 1
// baseline (495.471 us; speedup 1.0000x reference)
//
#include <hip/hip_runtime.h>
#include <hip/hip_bf16.h>
#include <stdint.h>

#define T_    16
#define N_    32
#define C_    128
#define HW_   1024
#define COUT_ 128

typedef __bf16 bf16x8 __attribute__((ext_vector_type(8)));
typedef float  f32x4  __attribute__((ext_vector_type(4)));

// ---------------- K0: prep pw weights (bf16) + BN epilogue constants ----------------
__global__ __launch_bounds__(256) void k0_prep(
    const float* __restrict__ pw_w, const float* __restrict__ pw_b,
    const float* __restrict__ gamma, const float* __restrict__ beta,
    const float* __restrict__ mean,  const float* __restrict__ var,
    __bf16* __restrict__ wbf, float* __restrict__ scale2, float* __restrict__ bias2) {
  int idx = blockIdx.x * 256 + threadIdx.x;
  if (idx < COUT_ * C_) wbf[idx] = (__bf16)pw_w[idx];
  if (idx < COUT_) {
    float s = gamma[idx] * rsqrtf(var[idx] + 1e-5f);
    scale2[idx] = s;
    bias2[idx]  = beta[idx] + (pw_b[idx] - mean[idx]) * s;
  }
}

// ---------------- K1: LIF scan -> packed spike bits ----------------
// block = one (n,c); thread handles hw = {tid, tid+256, tid+512, tid+768}
// S layout (uint32 words): word[((n*128+c)*16 + t)*32 + row] = 32 col-bits of that row
__global__ __launch_bounds__(256) void k1_lif(const float* __restrict__ x,
                                              uint32_t* __restrict__ S) {
  int nc   = blockIdx.x;          // n*128 + c
  int tid  = threadIdx.x;
  int lane = tid & 63;
  int w    = tid >> 6;
  size_t base = (size_t)nc * HW_;
  unsigned long long* S64 = (unsigned long long*)S;

  float v0 = 0.f, v1 = 0.f, v2 = 0.f, v3 = 0.f;
#pragma unroll
  for (int t = 0; t < T_; ++t) {
    const float* xp = x + (size_t)t * (N_ * C_ * HW_) + base;
    float x0 = xp[tid];
    float x1 = xp[256 + tid];
    float x2 = xp[512 + tid];
    float x3 = xp[768 + tid];
    // v <- v + (x - v)/2 ; spike = (v >= 1) ; v <- spiked ? 0 : v
    v0 = v0 + (x0 - v0) * 0.5f; bool s0 = (v0 >= 1.0f); if (s0) v0 = 0.f;
    v1 = v1 + (x1 - v1) * 0.5f; bool s1 = (v1 >= 1.0f); if (s1) v1 = 0.f;
    v2 = v2 + (x2 - v2) * 0.5f; bool s2 = (v2 >= 1.0f); if (s2) v2 = 0.f;
    v3 = v3 + (x3 - v3) * 0.5f; bool s3 = (v3 >= 1.0f); if (s3) v3 = 0.f;
    unsigned long long m0 = __ballot(s0);
    unsigned long long m1 = __ballot(s1);
    unsigned long long m2 = __ballot(s2);
    unsigned long long m3 = __ballot(s3);
    if (lane == 0) {
      size_t b64 = ((size_t)nc * T_ + t) * 16;
      S64[b64 + 0  + w] = m0;   // covers hw [0*256 + w*64, +64)
      S64[b64 + 4  + w] = m1;
      S64[b64 + 8  + w] = m2;
      S64[b64 + 12 + w] = m3;
    }
  }
}

// ---------------- K2: spike bits -> depthwise (VALU) -> LDS B tile -> MFMA GEMM -> BN -> out ----
// block: one (n_img, row-group of 4 rows => 128 hw). 256 threads = 4 waves.
__global__ __launch_bounds__(256) void k2_main(
    const uint32_t* __restrict__ S,
    const float* __restrict__ dww, const float* __restrict__ dwb,
    const __bf16* __restrict__ wbf,
    const float* __restrict__ scale2, const float* __restrict__ bias2,
    float* __restrict__ out) {
  __shared__ uint32_t sb[C_ * 8];          // [c][8]: rows r0-1 .. r0+4 (6 used)
  __shared__ __bf16  Blds[128 * 136];      // [hw local 0..127][c], pitch 136 (16B-aligned rows)

  const int bid   = blockIdx.x;
  const int n_img = bid >> 3;              // t*N + n
  const int rg    = bid & 7;
  const int t_img = n_img >> 5;            // / N_
  const int n_in  = n_img & 31;
  const int r0    = rg * 4;
  const int tid   = threadIdx.x;

  // ---- Phase A: stage 128c x 6 spike row-words into LDS ----
#pragma unroll
  for (int k = 0; k < 3; ++k) {
    int li = k * 256 + tid;                // 0..767 = c*6 + ri
    int c  = li / 6;
    int ri = li - c * 6;
    int gr = r0 - 1 + ri;
    uint32_t wv = 0;
    if (gr >= 0 && gr < 32)
      wv = S[(((size_t)n_in * C_ + c) * T_ + t_img) * 32 + gr];
    sb[c * 8 + ri] = wv;
  }
  __syncthreads();

  // ---- Phase B: depthwise 3x3 from bits -> bf16 B tile [hw][c] ----
  {
    int c    = tid & 127;
    int half = tid >> 7;                    // wave-uniform
    float w9[9];
#pragma unroll
    for (int i = 0; i < 9; ++i) w9[i] = dww[c * 9 + i];
    float bias = dwb[c];
    uint64_t R[6];
#pragma unroll
    for (int q = 0; q < 6; ++q) R[q] = ((uint64_t)sb[c * 8 + q]) << 1;

    int col0 = half * 16;
#pragma unroll 4
    for (int ci = 0; ci < 16; ++ci) {
      int col = col0 + ci;
      float acc[4] = {bias, bias, bias, bias};
#pragma unroll
      for (int q = 0; q < 6; ++q) {
        uint32_t tri = (uint32_t)(R[q] >> col) & 7u;  // bits col-1,col,col+1 (zero-padded)
        float b0 = (float)(tri & 1u);
        float b1 = (float)((tri >> 1) & 1u);
        float b2 = (float)(tri >> 2);
#pragma unroll
        for (int kh = 0; kh < 3; ++kh) {
          int r = q - kh;                   // source row q = r + kh
          if (r >= 0 && r < 4) {
            acc[r] += w9[kh * 3 + 0] * b0;
            acc[r] += w9[kh * 3 + 1] * b1;
            acc[r] += w9[kh * 3 + 2] * b2;
          }
        }
      }
#pragma unroll
      for (int r = 0; r < 4; ++r)
        Blds[(r * 32 + col) * 136 + c] = (__bf16)acc[r];
    }
  }
  __syncthreads();

  // ---- Phase C: GEMM  out[o, hw] = sum_c pw[o,c] * B[c, hw], 4 waves: 2x2 of 64x64 ----
  const int lane  = tid & 63;
  const int wid   = tid >> 6;
  const int ohalf = wid >> 1;
  const int hhalf = wid & 1;
  const int m16   = lane & 15;
  const int q4    = lane >> 4;

  f32x4 acc[4][4];
#pragma unroll
  for (int mt = 0; mt < 4; ++mt)
#pragma unroll
    for (int nt = 0; nt < 4; ++nt)
      acc[mt][nt] = (f32x4){0.f, 0.f, 0.f, 0.f};

#pragma unroll
  for (int ks = 0; ks < 4; ++ks) {
    const int k0 = ks * 32 + q4 * 8;
    bf16x8 af[4], bfr[4];
#pragma unroll
    for (int mt = 0; mt < 4; ++mt) {
      int m = ohalf * 64 + mt * 16 + m16;
      af[mt] = *(const bf16x8*)(wbf + m * 128 + k0);
    }
#pragma unroll
    for (int nt = 0; nt < 4; ++nt) {
      int hw = hhalf * 64 + nt * 16 + m16;
      bfr[nt] = *(const bf16x8*)(Blds + hw * 136 + k0);
    }
#pragma unroll
    for (int nt = 0; nt < 4; ++nt)
#pragma unroll
      for (int mt = 0; mt < 4; ++mt)
        acc[mt][nt] = __builtin_amdgcn_mfma_f32_16x16x32_bf16(af[mt], bfr[nt], acc[mt][nt], 0, 0, 0);
  }

  // ---- Epilogue: BN fold + store ----
#pragma unroll
  for (int mt = 0; mt < 4; ++mt) {
    int ob = ohalf * 64 + mt * 16 + q4 * 4;
    f32x4 sc = *(const f32x4*)(scale2 + ob);
    f32x4 bs = *(const f32x4*)(bias2 + ob);
#pragma unroll
    for (int nt = 0; nt < 4; ++nt) {
      int hw = hhalf * 64 + nt * 16 + m16;
      size_t obase = (size_t)n_img * (COUT_ * HW_) + (size_t)rg * 128 + hw;
#pragma unroll
      for (int ri = 0; ri < 4; ++ri) {
        out[obase + (size_t)(ob + ri) * HW_] = acc[mt][nt][ri] * sc[ri] + bs[ri];
      }
    }
  }
}

// ---------------- launcher ----------------
extern "C" void kernel_launch(void* const* d_in, const int* in_sizes, int n_in_args,
                              void* d_out, int out_size, void* d_ws, size_t ws_size,
                              hipStream_t stream) {
  const float* x     = (const float*)d_in[0];
  const float* dw_w  = (const float*)d_in[1];
  const float* dw_b  = (const float*)d_in[2];
  const float* pw_w  = (const float*)d_in[3];
  const float* pw_b  = (const float*)d_in[4];
  const float* gamma = (const float*)d_in[5];
  const float* beta  = (const float*)d_in[6];
  const float* rmean = (const float*)d_in[7];
  const float* rvar  = (const float*)d_in[8];
  float* out = (float*)d_out;

  // ws layout: spikes 8 MB | wbf16 32 KB | scale2 512 B | bias2 512 B
  uint32_t* S    = (uint32_t*)d_ws;
  __bf16* wbf    = (__bf16*)((char*)d_ws + (size_t)N_ * C_ * T_ * 128);
  float* scale2  = (float*)((char*)wbf + (size_t)COUT_ * C_ * 2);
  float* bias2   = scale2 + COUT_;

  k0_prep<<<64, 256, 0, stream>>>(pw_w, pw_b, gamma, beta, rmean, rvar, wbf, scale2, bias2);
  k1_lif<<<N_ * C_, 256, 0, stream>>>(x, S);
  k2_main<<<(T_ * N_) * 8, 256, 0, stream>>>(S, dw_w, dw_b, wbf, scale2, bias2, out);
}